// Round 4
// baseline (1490.522 us; speedup 1.0000x reference)
//
#include <hip/hip_runtime.h>
#include <cstddef>
#include <cstdint>

#define Tn 512
#define Bn 512

typedef float f32x4 __attribute__((ext_vector_type(4)));

__device__ __forceinline__ float rlane(float v, int lane) {
    return __uint_as_float((unsigned)__builtin_amdgcn_readlane((int)__float_as_uint(v), lane));
}
__device__ __forceinline__ float sigm(float x) { return 1.0f / (1.0f + __expf(-x)); }
// tanh(x) = 1 - 2/(1+e^{2x}); inf-safe at both ends
__device__ __forceinline__ float tanhf_(float x) { return 1.0f - 2.0f / (1.0f + __expf(2.0f * x)); }

// LDS-visibility barrier WITHOUT the __syncthreads vmcnt(0) drain:
// global loads/stores stay in flight across steps.
#define BAR_LGKM() asm volatile("s_waitcnt lgkmcnt(0)\n\ts_barrier" ::: "memory")

// 24 K-steps; source lane indices are compile-time literals after unroll.
// Window [OFF, OFF+24) within a 64-lane source S0, crossing into S1 at SPLIT.
#define BODY24(S0, S1, OFF, SPLIT)                                     \
    _Pragma("unroll")                                                  \
    for (int kk = 0; kk < 24; ++kk) {                                  \
        const float v = (kk < (SPLIT)) ? rlane((S0), (OFF) + kk)       \
                                       : rlane((S1), (OFF) + kk - 64); \
        a0 = fmaf(v, w0[kk >> 2][kk & 3], a0);                         \
        a1 = fmaf(v, w1[kk >> 2][kk & 3], a1);                         \
        a2 = fmaf(v, w2[kk >> 2][kk & 3], a2);                         \
        a3 = fmaf(v, w3[kk >> 2][kk & 3], a3);                         \
    }

// ---------------------------------------------------------------------------
// Layer 0 (IN=1). One (b,dir) task per 128-thread block (2 waves, K=32 each).
// Weights: f32x4 w0..w3[8] = 128 regs; live set ~165 << 256 budget of
// __launch_bounds__(128,2) -> pure-VGPR allocation (no AGPR stash).
// Both waves redundantly reduce the 2 partials + activate (identical order ->
// bit-identical h). Per-step h store is never vmcnt-drained.
// ---------------------------------------------------------------------------
__global__ __launch_bounds__(128, 2) void k_lstm_l0(
    const float* __restrict__ x,
    const float* __restrict__ wih_f, const float* __restrict__ whh_f,
    const float* __restrict__ bih_f, const float* __restrict__ bhh_f,
    const float* __restrict__ wih_r, const float* __restrict__ whh_r,
    const float* __restrict__ bih_r, const float* __restrict__ bhh_r,
    float* __restrict__ h0)
{
    const int tid = threadIdx.x;
    const int kh  = tid >> 6;        // K half: 0 -> h[0:32), 1 -> h[32:64)
    const int j   = tid & 63;        // hidden unit
    const int b   = blockIdx.x >> 1;
    const int dir = blockIdx.x & 1;
    const int klo = kh * 32;

    const float* __restrict__ wih = dir ? wih_r : wih_f;
    const float* __restrict__ whh = dir ? whh_r : whh_f;
    const float* __restrict__ bih = dir ? bih_r : bih_f;
    const float* __restrict__ bhh = dir ? bhh_r : bhh_f;

    __shared__ float  xs[Tn];           // 2 KB
    __shared__ float4 part[2][2][64];   // 4 KB

    #pragma unroll
    for (int i = 0; i < Tn / 128; ++i) xs[i * 128 + tid] = x[(size_t)b * Tn + i * 128 + tid];

    f32x4 w0[8], w1[8], w2[8], w3[8];
    float wx[4], bias[4];
    #pragma unroll
    for (int g = 0; g < 4; ++g) {
        const int r = g * 64 + j;
        wx[g]   = wih[r];               // IN == 1
        bias[g] = bih[r] + bhh[r];
    }
    #pragma unroll
    for (int ci = 0; ci < 8; ++ci) {
        w0[ci] = *reinterpret_cast<const f32x4*>(whh + (size_t)(0 * 64 + j) * 64 + klo + ci * 4);
        w1[ci] = *reinterpret_cast<const f32x4*>(whh + (size_t)(1 * 64 + j) * 64 + klo + ci * 4);
        w2[ci] = *reinterpret_cast<const f32x4*>(whh + (size_t)(2 * 64 + j) * 64 + klo + ci * 4);
        w3[ci] = *reinterpret_cast<const f32x4*>(whh + (size_t)(3 * 64 + j) * 64 + klo + ci * 4);
    }
    __syncthreads();   // once: xs visible

    float h = 0.0f, c = 0.0f;
    float* __restrict__ outp = h0 + (size_t)b * Tn * 128 + dir * 64 + j;

    for (int s = 0; s < Tn; ++s) {
        const int t  = dir ? (Tn - 1 - s) : s;
        const int bf = s & 1;
        const float xt = xs[t];

        float a0 = 0.0f, a1 = 0.0f, a2 = 0.0f, a3 = 0.0f;
        if (kh == 0) {   // wave-uniform
            #pragma unroll
            for (int kk = 0; kk < 32; ++kk) {
                const float v = rlane(h, kk);
                a0 = fmaf(v, w0[kk >> 2][kk & 3], a0);
                a1 = fmaf(v, w1[kk >> 2][kk & 3], a1);
                a2 = fmaf(v, w2[kk >> 2][kk & 3], a2);
                a3 = fmaf(v, w3[kk >> 2][kk & 3], a3);
            }
        } else {
            #pragma unroll
            for (int kk = 0; kk < 32; ++kk) {
                const float v = rlane(h, 32 + kk);
                a0 = fmaf(v, w0[kk >> 2][kk & 3], a0);
                a1 = fmaf(v, w1[kk >> 2][kk & 3], a1);
                a2 = fmaf(v, w2[kk >> 2][kk & 3], a2);
                a3 = fmaf(v, w3[kk >> 2][kk & 3], a3);
            }
        }
        part[bf][kh][j] = make_float4(a0, a1, a2, a3);
        BAR_LGKM();
        const float4 pA = part[bf][0][j];
        const float4 pB = part[bf][1][j];
        const float gi = fmaf(xt, wx[0], bias[0]) + pA.x + pB.x;
        const float gf = fmaf(xt, wx[1], bias[1]) + pA.y + pB.y;
        const float gg = fmaf(xt, wx[2], bias[2]) + pA.z + pB.z;
        const float go = fmaf(xt, wx[3], bias[3]) + pA.w + pB.w;
        c = sigm(gf) * c + sigm(gi) * tanhf_(gg);
        h = sigm(go) * tanhf_(c);
        if (kh == 0) outp[(size_t)t * 128] = h;   // wave-uniform
    }
}

// ---------------------------------------------------------------------------
// Layer 1 forward scan, input GEMM fused (K = 128 input + 64 recurrent = 192).
// One batch element per 512-thread block; K split 24/wave over 8 waves ->
// f32x4 w0..w3[6] = 96 weight regs, live ~135 << 256 budget of (512,2).
// K windows (wave -> source, literal offsets):
//   w0:x1a[0:24) w1:x1a[24:48) w2:x1a[48:64)+x1b[0:8) w3:x1b[8:32)
//   w4:x1b[32:56) w5:x1b[56:64)+h[0:16) w6:h[16:40) w7:h[40:64)
// Waves 0-4: pure producers (prefetch next x1; raw barrier never drains vmcnt
// -> HBM latency hides under the step). Waves 5-7: produce + redundantly
// reduce all 8 partials in fixed order + activate (bit-identical h).
// ---------------------------------------------------------------------------
__global__ __launch_bounds__(512, 2) void k_lstm_l1f(
    const float* __restrict__ h0,
    const float* __restrict__ wih, const float* __restrict__ whh,
    const float* __restrict__ bih, const float* __restrict__ bhh,
    float* __restrict__ h1last)
{
    const int tid = threadIdx.x;
    const int wv  = tid >> 6;        // 0..7
    const int j   = tid & 63;
    const int b   = blockIdx.x;
    const int kbase = wv * 24;

    __shared__ float4 part[2][8][64];   // 16 KB

    float bias[4];
    #pragma unroll
    for (int g = 0; g < 4; ++g) bias[g] = bih[g * 64 + j] + bhh[g * 64 + j];

    f32x4 w0[6], w1[6], w2[6], w3[6];
    #pragma unroll
    for (int ci = 0; ci < 6; ++ci) {
        const int k = kbase + ci * 4;   // chunk never straddles the 128 boundary
        w0[ci] = *reinterpret_cast<const f32x4*>((k < 128)
            ? wih + (size_t)(0 * 64 + j) * 128 + k : whh + (size_t)(0 * 64 + j) * 64 + (k - 128));
        w1[ci] = *reinterpret_cast<const f32x4*>((k < 128)
            ? wih + (size_t)(1 * 64 + j) * 128 + k : whh + (size_t)(1 * 64 + j) * 64 + (k - 128));
        w2[ci] = *reinterpret_cast<const f32x4*>((k < 128)
            ? wih + (size_t)(2 * 64 + j) * 128 + k : whh + (size_t)(2 * 64 + j) * 64 + (k - 128));
        w3[ci] = *reinterpret_cast<const f32x4*>((k < 128)
            ? wih + (size_t)(3 * 64 + j) * 128 + k : whh + (size_t)(3 * 64 + j) * 64 + (k - 128));
    }

    const float* __restrict__ xrow = h0 + (size_t)b * Tn * 128;

    float x1a = 0.0f, x1b = 0.0f, h = 0.0f, c = 0.0f;
    if (wv <= 2)            x1a = xrow[j];
    if (wv >= 2 && wv <= 5) x1b = xrow[64 + j];

    for (int t = 0; t < Tn; ++t) {
        const int bf = t & 1;
        const int tn = (t + 1 < Tn) ? (t + 1) : t;
        // per-wave prefetch of only the needed sources (wave-uniform branches)
        float nx1a = x1a, nx1b = x1b;
        if (wv <= 2)            nx1a = xrow[(size_t)tn * 128 + j];
        if (wv >= 2 && wv <= 5) nx1b = xrow[(size_t)tn * 128 + 64 + j];

        float a0 = 0.0f, a1 = 0.0f, a2 = 0.0f, a3 = 0.0f;
        switch (wv) {   // wave-uniform; all rlane indices literal
            case 0:  BODY24(x1a, x1a,  0, 24); break;
            case 1:  BODY24(x1a, x1a, 24, 24); break;
            case 2:  BODY24(x1a, x1b, 48, 16); break;
            case 3:  BODY24(x1b, x1b,  8, 24); break;
            case 4:  BODY24(x1b, x1b, 32, 24); break;
            case 5:  BODY24(x1b, h,   56,  8); break;
            case 6:  BODY24(h,   h,   16, 24); break;
            default: BODY24(h,   h,   40, 24); break;
        }
        part[bf][wv][j] = make_float4(a0, a1, a2, a3);
        BAR_LGKM();
        if (wv >= 5) {   // reducers: identical fixed-order reduce + activate
            const float4 q0 = part[bf][0][j];
            const float4 q1 = part[bf][1][j];
            const float4 q2 = part[bf][2][j];
            const float4 q3 = part[bf][3][j];
            const float4 q4 = part[bf][4][j];
            const float4 q5 = part[bf][5][j];
            const float4 q6 = part[bf][6][j];
            const float4 q7 = part[bf][7][j];
            const float gi = bias[0] + q0.x + q1.x + q2.x + q3.x + q4.x + q5.x + q6.x + q7.x;
            const float gf = bias[1] + q0.y + q1.y + q2.y + q3.y + q4.y + q5.y + q6.y + q7.y;
            const float gg = bias[2] + q0.z + q1.z + q2.z + q3.z + q4.z + q5.z + q6.z + q7.z;
            const float go = bias[3] + q0.w + q1.w + q2.w + q3.w + q4.w + q5.w + q6.w + q7.w;
            c = sigm(gf) * c + sigm(gi) * tanhf_(gg);
            h = sigm(go) * tanhf_(c);
        }
        x1a = nx1a; x1b = nx1b;
    }
    if (wv == 6) h1last[(size_t)b * 64 + j] = h;
}

// ---------------------------------------------------------------------------
// Layer-1 backward direction collapses to ONE step at t=T-1 (zero init state),
// then the final FC. One wave per batch element.
// ---------------------------------------------------------------------------
__global__ __launch_bounds__(64, 1) void k_l1r_fc(
    const float* __restrict__ h0,
    const float* __restrict__ wihr,
    const float* __restrict__ bihr, const float* __restrict__ bhhr,
    const float* __restrict__ h1last,
    const float* __restrict__ fcw, const float* __restrict__ fcb,
    float* __restrict__ out)
{
    const int b = blockIdx.x;
    const int j = threadIdx.x;
    const float* __restrict__ xrow = h0 + ((size_t)b * Tn + (Tn - 1)) * 128;
    const float x1a = xrow[j];
    const float x1b = xrow[64 + j];
    float acc[4];
    #pragma unroll
    for (int g = 0; g < 4; ++g) {
        const int r = g * 64 + j;
        float a = bihr[r] + bhhr[r];
        const float* __restrict__ wr = wihr + (size_t)r * 128;
        #pragma unroll
        for (int d4 = 0; d4 < 16; ++d4) {
            const float4 w4 = *reinterpret_cast<const float4*>(&wr[d4 * 4]);
            a = fmaf(rlane(x1a, d4 * 4 + 0), w4.x, a);
            a = fmaf(rlane(x1a, d4 * 4 + 1), w4.y, a);
            a = fmaf(rlane(x1a, d4 * 4 + 2), w4.z, a);
            a = fmaf(rlane(x1a, d4 * 4 + 3), w4.w, a);
        }
        #pragma unroll
        for (int d4 = 0; d4 < 16; ++d4) {
            const float4 w4 = *reinterpret_cast<const float4*>(&wr[64 + d4 * 4]);
            a = fmaf(rlane(x1b, d4 * 4 + 0), w4.x, a);
            a = fmaf(rlane(x1b, d4 * 4 + 1), w4.y, a);
            a = fmaf(rlane(x1b, d4 * 4 + 2), w4.z, a);
            a = fmaf(rlane(x1b, d4 * 4 + 3), w4.w, a);
        }
        acc[g] = a;
    }
    const float cr = sigm(acc[0]) * tanhf_(acc[2]);
    const float hr = sigm(acc[3]) * tanhf_(cr);
    float v = h1last[(size_t)b * 64 + j] * fcw[j] + hr * fcw[64 + j];
    #pragma unroll
    for (int off = 32; off > 0; off >>= 1) v += __shfl_xor(v, off, 64);
    if (j == 0) out[b] = v + fcb[0];
}

// ---------------------------------------------------------------------------
extern "C" void kernel_launch(void* const* d_in, const int* in_sizes, int n_in,
                              void* d_out, int out_size, void* d_ws, size_t ws_size,
                              hipStream_t stream)
{
    const float* x       = (const float*)d_in[0];
    const float* wih_l0  = (const float*)d_in[1];
    const float* whh_l0  = (const float*)d_in[2];
    const float* bih_l0  = (const float*)d_in[3];
    const float* bhh_l0  = (const float*)d_in[4];
    const float* wih_l0r = (const float*)d_in[5];
    const float* whh_l0r = (const float*)d_in[6];
    const float* bih_l0r = (const float*)d_in[7];
    const float* bhh_l0r = (const float*)d_in[8];
    const float* wih_l1  = (const float*)d_in[9];
    const float* whh_l1  = (const float*)d_in[10];
    const float* bih_l1  = (const float*)d_in[11];
    const float* bhh_l1  = (const float*)d_in[12];
    const float* wih_l1r = (const float*)d_in[13];
    const float* whh_l1r = (const float*)d_in[14];
    const float* bih_l1r = (const float*)d_in[15];
    const float* bhh_l1r = (const float*)d_in[16];
    const float* fcw     = (const float*)d_in[17];
    const float* fcb     = (const float*)d_in[18];
    (void)whh_l1r; (void)in_sizes; (void)n_in; (void)out_size;

    // ws layout: h0 [512][512][128] f32 (134.2 MB) + h1last [512][64] f32
    float* h0     = (float*)d_ws;
    float* h1last = h0 + (size_t)Bn * Tn * 128;
    (void)ws_size;

    k_lstm_l0<<<dim3(Bn * 2), dim3(128), 0, stream>>>(
        x, wih_l0, whh_l0, bih_l0, bhh_l0,
        wih_l0r, whh_l0r, bih_l0r, bhh_l0r, h0);
    k_lstm_l1f<<<dim3(Bn), dim3(512), 0, stream>>>(
        h0, wih_l1, whh_l1, bih_l1, bhh_l1, h1last);
    k_l1r_fc<<<dim3(Bn), dim3(64), 0, stream>>>(
        h0, wih_l1r, bih_l1r, bhh_l1r, h1last, fcw, fcb, (float*)d_out);
}

// Round 5
// 1397.601 us; speedup vs baseline: 1.0665x; 1.0665x over previous
//
#include <hip/hip_runtime.h>
#include <cstddef>
#include <cstdint>

#define Tn 512
#define Bn 512

typedef float f32x4 __attribute__((ext_vector_type(4)));

__device__ __forceinline__ float rlane(float v, int lane) {
    return __uint_as_float((unsigned)__builtin_amdgcn_readlane((int)__float_as_uint(v), lane));
}
__device__ __forceinline__ float sigm(float x) { return 1.0f / (1.0f + __expf(-x)); }
// tanh(x) = 1 - 2/(1+e^{2x}); inf-safe at both ends
__device__ __forceinline__ float tanhf_(float x) { return 1.0f - 2.0f / (1.0f + __expf(2.0f * x)); }

// LDS-visibility barrier WITHOUT the __syncthreads vmcnt(0) drain.
#define BAR_LGKM() asm volatile("s_waitcnt lgkmcnt(0)\n\ts_barrier" ::: "memory")
// Pin a value into arch-VGPR class (anti-AGPR-stash hammer).
#define PIN4(v) asm volatile("" : "+v"(v))

#define ACT(GI, GF, GG, GO, C, H)                              \
    do {                                                       \
        C = sigm(GF) * (C) + sigm(GI) * tanhf_(GG);            \
        H = sigm(GO) * tanhf_(C);                              \
    } while (0)

// ---------------------------------------------------------------------------
// Layer 0 (IN=1). Block = 128 thr = 2 waves handling TWO batch elements of one
// direction. Wave kh owns K-half [32kh,32kh+32); weights f32x4 wt[4][8] =
// 128 VGPRs, SHARED by both element-chains (the point of 2-elem/wave), pinned
// to VGPR class. __launch_bounds__(128,1) -> 512-reg budget, huge slack.
// Two independent recurrences interleave in-wave -> latency hidden.
// Both waves redundantly reduce + activate (bit-identical h).
// ---------------------------------------------------------------------------
__global__ __launch_bounds__(128, 1) void k_lstm_l0(
    const float* __restrict__ x,
    const float* __restrict__ wih_f, const float* __restrict__ whh_f,
    const float* __restrict__ bih_f, const float* __restrict__ bhh_f,
    const float* __restrict__ wih_r, const float* __restrict__ whh_r,
    const float* __restrict__ bih_r, const float* __restrict__ bhh_r,
    float* __restrict__ h0out)
{
    const int tid = threadIdx.x;
    const int kh  = tid >> 6;        // K half
    const int j   = tid & 63;        // hidden unit
    const int dir = blockIdx.x & 1;
    const int b0  = (blockIdx.x >> 1) * 2;
    const int b1  = b0 + 1;
    const int klo = kh * 32;

    const float* __restrict__ wih = dir ? wih_r : wih_f;
    const float* __restrict__ whh = dir ? whh_r : whh_f;
    const float* __restrict__ bih = dir ? bih_r : bih_f;
    const float* __restrict__ bhh = dir ? bhh_r : bhh_f;

    __shared__ float  xs[2][Tn];            // 4 KB
    __shared__ float4 part[2][2][2][64];    // [elem][buf][kh][unit], 8 KB

    #pragma unroll
    for (int i = 0; i < Tn / 128; ++i) {
        xs[0][i * 128 + tid] = x[(size_t)b0 * Tn + i * 128 + tid];
        xs[1][i * 128 + tid] = x[(size_t)b1 * Tn + i * 128 + tid];
    }

    f32x4 wt[4][8];
    float wx[4], bias[4];
    #pragma unroll
    for (int g = 0; g < 4; ++g) {
        const int r = g * 64 + j;
        wx[g]   = wih[r];               // IN == 1
        bias[g] = bih[r] + bhh[r];
        #pragma unroll
        for (int ci = 0; ci < 8; ++ci) {
            wt[g][ci] = *reinterpret_cast<const f32x4*>(whh + (size_t)r * 64 + klo + ci * 4);
            PIN4(wt[g][ci]);
        }
    }
    __syncthreads();   // once: xs visible

    float hA = 0.0f, cA = 0.0f, hB = 0.0f, cB = 0.0f;
    float* __restrict__ opA = h0out + (size_t)b0 * Tn * 128 + dir * 64 + j;
    float* __restrict__ opB = h0out + (size_t)b1 * Tn * 128 + dir * 64 + j;

    for (int s = 0; s < Tn; ++s) {
        const int t  = dir ? (Tn - 1 - s) : s;
        const int bf = s & 1;
        const float xtA = xs[0][t];
        const float xtB = xs[1][t];

        float a0, a1, a2, a3;
#define L0B(HS, BASE)                                          \
        a0 = a1 = a2 = a3 = 0.0f;                              \
        _Pragma("unroll")                                      \
        for (int kk = 0; kk < 32; ++kk) {                      \
            const float v = rlane((HS), (BASE) + kk);          \
            a0 = fmaf(v, wt[0][kk >> 2][kk & 3], a0);          \
            a1 = fmaf(v, wt[1][kk >> 2][kk & 3], a1);          \
            a2 = fmaf(v, wt[2][kk >> 2][kk & 3], a2);          \
            a3 = fmaf(v, wt[3][kk >> 2][kk & 3], a3);          \
        }
        if (kh == 0) {   // wave-uniform
            L0B(hA, 0);  part[0][bf][0][j] = make_float4(a0, a1, a2, a3);
            L0B(hB, 0);  part[1][bf][0][j] = make_float4(a0, a1, a2, a3);
        } else {
            L0B(hA, 32); part[0][bf][1][j] = make_float4(a0, a1, a2, a3);
            L0B(hB, 32); part[1][bf][1][j] = make_float4(a0, a1, a2, a3);
        }
#undef L0B
        BAR_LGKM();
        {
            const float4 pA = part[0][bf][0][j];
            const float4 pB = part[0][bf][1][j];
            const float gi = fmaf(xtA, wx[0], bias[0]) + pA.x + pB.x;
            const float gf = fmaf(xtA, wx[1], bias[1]) + pA.y + pB.y;
            const float gg = fmaf(xtA, wx[2], bias[2]) + pA.z + pB.z;
            const float go = fmaf(xtA, wx[3], bias[3]) + pA.w + pB.w;
            ACT(gi, gf, gg, go, cA, hA);
        }
        {
            const float4 pA = part[1][bf][0][j];
            const float4 pB = part[1][bf][1][j];
            const float gi = fmaf(xtB, wx[0], bias[0]) + pA.x + pB.x;
            const float gf = fmaf(xtB, wx[1], bias[1]) + pA.y + pB.y;
            const float gg = fmaf(xtB, wx[2], bias[2]) + pA.z + pB.z;
            const float go = fmaf(xtB, wx[3], bias[3]) + pA.w + pB.w;
            ACT(gi, gf, gg, go, cB, hB);
        }
        if (kh == 0) opA[(size_t)t * 128] = hA;   // wave-uniform
        else         opB[(size_t)t * 128] = hB;
    }
}

// ---------------------------------------------------------------------------
// Layer 1 forward scan, fused input GEMM (K = 128 x + 64 h). Block = 256 thr
// = 4 waves handling TWO batch elements. Wave wv owns x-K [32wv,32wv+32) and
// h-K [16wv,16wv+16): post-activation tail is only 64 FMAs per wave
// (balanced). Weights wxq[4][8]+whq[4][4] = 192 VGPRs, shared by both chains,
// pinned. (256,1) -> 512-reg budget. All waves redundantly reduce+activate.
// Per-step x prefetch floats across the raw lgkm-only barrier.
// ---------------------------------------------------------------------------
__global__ __launch_bounds__(256, 1) void k_lstm_l1f(
    const float* __restrict__ h0in,
    const float* __restrict__ wih, const float* __restrict__ whh,
    const float* __restrict__ bih, const float* __restrict__ bhh,
    float* __restrict__ h1last)
{
    const int tid = threadIdx.x;
    const int wv  = tid >> 6;        // 0..3
    const int j   = tid & 63;
    const int b0  = blockIdx.x * 2;
    const int b1  = b0 + 1;

    __shared__ float4 part[2][2][4][64];   // [elem][buf][wv][unit], 16 KB

    f32x4 wxq[4][8], whq[4][4];
    float bias[4];
    #pragma unroll
    for (int g = 0; g < 4; ++g) {
        const int r = g * 64 + j;
        bias[g] = bih[r] + bhh[r];
        #pragma unroll
        for (int ci = 0; ci < 8; ++ci) {
            wxq[g][ci] = *reinterpret_cast<const f32x4*>(wih + (size_t)r * 128 + wv * 32 + ci * 4);
            PIN4(wxq[g][ci]);
        }
        #pragma unroll
        for (int ci = 0; ci < 4; ++ci) {
            whq[g][ci] = *reinterpret_cast<const f32x4*>(whh + (size_t)r * 64 + wv * 16 + ci * 4);
            PIN4(whq[g][ci]);
        }
    }

    const float* __restrict__ xrowA = h0in + (size_t)b0 * Tn * 128;
    const float* __restrict__ xrowB = h0in + (size_t)b1 * Tn * 128;
    const int xoff = (wv >> 1) * 64;   // waves 0,1: x1[0:64); waves 2,3: x1[64:128)

    float sA = xrowA[xoff + j];
    float sB = xrowB[xoff + j];
    float hA = 0.0f, cA = 0.0f, hB = 0.0f, cB = 0.0f;

    for (int t = 0; t < Tn; ++t) {
        const int bf = t & 1;
        const int tn = (t + 1 < Tn) ? t + 1 : t;
        const float nsA = xrowA[(size_t)tn * 128 + xoff + j];   // prefetch
        const float nsB = xrowB[(size_t)tn * 128 + xoff + j];

        float a0, a1, a2, a3;
#define XB(S, BASE)                                            \
        a0 = a1 = a2 = a3 = 0.0f;                              \
        _Pragma("unroll")                                      \
        for (int kk = 0; kk < 32; ++kk) {                      \
            const float v = rlane((S), (BASE) + kk);           \
            a0 = fmaf(v, wxq[0][kk >> 2][kk & 3], a0);         \
            a1 = fmaf(v, wxq[1][kk >> 2][kk & 3], a1);         \
            a2 = fmaf(v, wxq[2][kk >> 2][kk & 3], a2);         \
            a3 = fmaf(v, wxq[3][kk >> 2][kk & 3], a3);         \
        }
#define HB(S, BASE)                                            \
        _Pragma("unroll")                                      \
        for (int kk = 0; kk < 16; ++kk) {                      \
            const float v = rlane((S), (BASE) + kk);           \
            a0 = fmaf(v, whq[0][kk >> 2][kk & 3], a0);         \
            a1 = fmaf(v, whq[1][kk >> 2][kk & 3], a1);         \
            a2 = fmaf(v, whq[2][kk >> 2][kk & 3], a2);         \
            a3 = fmaf(v, whq[3][kk >> 2][kk & 3], a3);         \
        }
        switch (wv) {   // wave-uniform; all rlane indices literal
        case 0:
            XB(sA, 0);  HB(hA, 0);  part[0][bf][0][j] = make_float4(a0, a1, a2, a3);
            XB(sB, 0);  HB(hB, 0);  part[1][bf][0][j] = make_float4(a0, a1, a2, a3);
            break;
        case 1:
            XB(sA, 32); HB(hA, 16); part[0][bf][1][j] = make_float4(a0, a1, a2, a3);
            XB(sB, 32); HB(hB, 16); part[1][bf][1][j] = make_float4(a0, a1, a2, a3);
            break;
        case 2:
            XB(sA, 0);  HB(hA, 32); part[0][bf][2][j] = make_float4(a0, a1, a2, a3);
            XB(sB, 0);  HB(hB, 32); part[1][bf][2][j] = make_float4(a0, a1, a2, a3);
            break;
        default:
            XB(sA, 32); HB(hA, 48); part[0][bf][3][j] = make_float4(a0, a1, a2, a3);
            XB(sB, 32); HB(hB, 48); part[1][bf][3][j] = make_float4(a0, a1, a2, a3);
            break;
        }
#undef XB
#undef HB
        BAR_LGKM();
        {
            const float4 q0 = part[0][bf][0][j];
            const float4 q1 = part[0][bf][1][j];
            const float4 q2 = part[0][bf][2][j];
            const float4 q3 = part[0][bf][3][j];
            const float gi = bias[0] + q0.x + q1.x + q2.x + q3.x;
            const float gf = bias[1] + q0.y + q1.y + q2.y + q3.y;
            const float gg = bias[2] + q0.z + q1.z + q2.z + q3.z;
            const float go = bias[3] + q0.w + q1.w + q2.w + q3.w;
            ACT(gi, gf, gg, go, cA, hA);
        }
        {
            const float4 q0 = part[1][bf][0][j];
            const float4 q1 = part[1][bf][1][j];
            const float4 q2 = part[1][bf][2][j];
            const float4 q3 = part[1][bf][3][j];
            const float gi = bias[0] + q0.x + q1.x + q2.x + q3.x;
            const float gf = bias[1] + q0.y + q1.y + q2.y + q3.y;
            const float gg = bias[2] + q0.z + q1.z + q2.z + q3.z;
            const float go = bias[3] + q0.w + q1.w + q2.w + q3.w;
            ACT(gi, gf, gg, go, cB, hB);
        }
        sA = nsA; sB = nsB;
    }
    if (wv == 0) h1last[(size_t)b0 * 64 + j] = hA;
    if (wv == 1) h1last[(size_t)b1 * 64 + j] = hB;
}

// ---------------------------------------------------------------------------
// Layer-1 backward direction collapses to ONE step at t=T-1 (zero init state),
// then the final FC. One wave per batch element.
// ---------------------------------------------------------------------------
__global__ __launch_bounds__(64, 1) void k_l1r_fc(
    const float* __restrict__ h0in,
    const float* __restrict__ wihr,
    const float* __restrict__ bihr, const float* __restrict__ bhhr,
    const float* __restrict__ h1last,
    const float* __restrict__ fcw, const float* __restrict__ fcb,
    float* __restrict__ out)
{
    const int b = blockIdx.x;
    const int j = threadIdx.x;
    const float* __restrict__ xrow = h0in + ((size_t)b * Tn + (Tn - 1)) * 128;
    const float x1a = xrow[j];
    const float x1b = xrow[64 + j];
    float acc[4];
    #pragma unroll
    for (int g = 0; g < 4; ++g) {
        const int r = g * 64 + j;
        float a = bihr[r] + bhhr[r];
        const float* __restrict__ wr = wihr + (size_t)r * 128;
        #pragma unroll
        for (int d4 = 0; d4 < 16; ++d4) {
            const float4 w4 = *reinterpret_cast<const float4*>(&wr[d4 * 4]);
            a = fmaf(rlane(x1a, d4 * 4 + 0), w4.x, a);
            a = fmaf(rlane(x1a, d4 * 4 + 1), w4.y, a);
            a = fmaf(rlane(x1a, d4 * 4 + 2), w4.z, a);
            a = fmaf(rlane(x1a, d4 * 4 + 3), w4.w, a);
        }
        #pragma unroll
        for (int d4 = 0; d4 < 16; ++d4) {
            const float4 w4 = *reinterpret_cast<const float4*>(&wr[64 + d4 * 4]);
            a = fmaf(rlane(x1b, d4 * 4 + 0), w4.x, a);
            a = fmaf(rlane(x1b, d4 * 4 + 1), w4.y, a);
            a = fmaf(rlane(x1b, d4 * 4 + 2), w4.z, a);
            a = fmaf(rlane(x1b, d4 * 4 + 3), w4.w, a);
        }
        acc[g] = a;
    }
    const float cr = sigm(acc[0]) * tanhf_(acc[2]);
    const float hr = sigm(acc[3]) * tanhf_(cr);
    float v = h1last[(size_t)b * 64 + j] * fcw[j] + hr * fcw[64 + j];
    #pragma unroll
    for (int off = 32; off > 0; off >>= 1) v += __shfl_xor(v, off, 64);
    if (j == 0) out[b] = v + fcb[0];
}

// ---------------------------------------------------------------------------
extern "C" void kernel_launch(void* const* d_in, const int* in_sizes, int n_in,
                              void* d_out, int out_size, void* d_ws, size_t ws_size,
                              hipStream_t stream)
{
    const float* x       = (const float*)d_in[0];
    const float* wih_l0  = (const float*)d_in[1];
    const float* whh_l0  = (const float*)d_in[2];
    const float* bih_l0  = (const float*)d_in[3];
    const float* bhh_l0  = (const float*)d_in[4];
    const float* wih_l0r = (const float*)d_in[5];
    const float* whh_l0r = (const float*)d_in[6];
    const float* bih_l0r = (const float*)d_in[7];
    const float* bhh_l0r = (const float*)d_in[8];
    const float* wih_l1  = (const float*)d_in[9];
    const float* whh_l1  = (const float*)d_in[10];
    const float* bih_l1  = (const float*)d_in[11];
    const float* bhh_l1  = (const float*)d_in[12];
    const float* wih_l1r = (const float*)d_in[13];
    const float* whh_l1r = (const float*)d_in[14];
    const float* bih_l1r = (const float*)d_in[15];
    const float* bhh_l1r = (const float*)d_in[16];
    const float* fcw     = (const float*)d_in[17];
    const float* fcb     = (const float*)d_in[18];
    (void)whh_l1r; (void)in_sizes; (void)n_in; (void)out_size;

    // ws layout: h0 [512][512][128] f32 (134.2 MB) + h1last [512][64] f32
    float* h0     = (float*)d_ws;
    float* h1last = h0 + (size_t)Bn * Tn * 128;
    (void)ws_size;

    k_lstm_l0<<<dim3(Bn), dim3(128), 0, stream>>>(          // 512 blocks: (pair, dir)
        x, wih_l0, whh_l0, bih_l0, bhh_l0,
        wih_l0r, whh_l0r, bih_l0r, bhh_l0r, h0);
    k_lstm_l1f<<<dim3(Bn / 2), dim3(256), 0, stream>>>(     // 256 blocks: pair
        h0, wih_l1, whh_l1, bih_l1, bhh_l1, h1last);
    k_l1r_fc<<<dim3(Bn), dim3(64), 0, stream>>>(
        h0, wih_l1r, bih_l1r, bhh_l1r, h1last, fcw, fcb, (float*)d_out);
}